// Round 3
// baseline (306.436 us; speedup 1.0000x reference)
//
#include <hip/hip_runtime.h>

#define NROWS 8000
#define DDIM 9
#define NCOL4 (NROWS / 4)      // 2000 float4 per output row
#define ROWS_PER_BLK 50        // 160 row-chunks
#define SCAN_T 1024
#define RPT 8                  // 1024 * 8 = 8192 >= 8000

typedef float f32x4 __attribute__((ext_vector_type(4)));  // native vec for nt-store

// ---------------------------------------------------------------------------
// Kernel 1 (single block): fused per-row reductions + cumsum scan.
//   s1/s2[r] = sum_j ((x-c)/a)^2 ; f[r] = x.w + b
//   cumsum(s1), cumsum(s2) -> w1_bar = 1/(1+exp(cs1-cs2)), w2_bar = 1-w1_bar
// (log-space equivalent of cumprod(prod(exp(-t^2))) normalization)
// Outputs: w1b[8000], w2b[8000], f12[8000] as float2 (f1,f2) pairs.
// ---------------------------------------------------------------------------
__global__ __launch_bounds__(SCAN_T)
void anfis_prep(const float* __restrict__ x,
                const float* __restrict__ a1p, const float* __restrict__ c1p,
                const float* __restrict__ a2p, const float* __restrict__ c2p,
                const float* __restrict__ w_fc1, const float* __restrict__ b_fc1,
                const float* __restrict__ w_fc2, const float* __restrict__ b_fc2,
                float* __restrict__ w1bo, float* __restrict__ w2bo,
                float2* __restrict__ f12o) {
    __shared__ float sh1[SCAN_T];
    __shared__ float sh2[SCAN_T];
    const int t = threadIdx.x;
    const int r0 = t * RPT;

    const float inv_a1 = 1.0f / a1p[0];
    const float c1 = c1p[0];
    const float inv_a2 = 1.0f / a2p[0];
    const float c2 = c2p[0];
    const float bb1 = b_fc1[0];
    const float bb2 = b_fc2[0];
    float wf1[DDIM], wf2[DDIM];
#pragma unroll
    for (int j = 0; j < DDIM; ++j) { wf1[j] = w_fc1[j]; wf2[j] = w_fc2[j]; }

    // per-thread: compute s1,s2,f for 8 consecutive rows; local inclusive cumsum
    float cs1[RPT], cs2[RPT];
    float run1 = 0.f, run2 = 0.f;
#pragma unroll
    for (int k = 0; k < RPT; ++k) {
        int r = r0 + k;
        float s1 = 0.f, s2 = 0.f, d1 = 0.f, d2 = 0.f;
        if (r < NROWS) {
#pragma unroll
            for (int j = 0; j < DDIM; ++j) {
                float xv = x[r * DDIM + j];
                float t1 = (xv - c1) * inv_a1;
                float t2 = (xv - c2) * inv_a2;
                s1 += t1 * t1;
                s2 += t2 * t2;
                d1 += xv * wf1[j];
                d2 += xv * wf2[j];
            }
            f12o[r] = make_float2(d1 + bb1, d2 + bb2);
        }
        run1 += s1;
        run2 += s2;
        cs1[k] = run1;
        cs2[k] = run2;
    }
    sh1[t] = run1;
    sh2[t] = run2;
    __syncthreads();
    // Hillis-Steele inclusive scan over thread totals
    for (int off = 1; off < SCAN_T; off <<= 1) {
        float v1 = 0.f, v2 = 0.f;
        if (t >= off) { v1 = sh1[t - off]; v2 = sh2[t - off]; }
        __syncthreads();
        sh1[t] += v1;
        sh2[t] += v2;
        __syncthreads();
    }
    const float pre1 = (t > 0) ? sh1[t - 1] : 0.f;
    const float pre2 = (t > 0) ? sh2[t - 1] : 0.f;
#pragma unroll
    for (int k = 0; k < RPT; ++k) {
        int r = r0 + k;
        if (r < NROWS) {
            float a = pre1 + cs1[k];   // cumsum s1 -> log w1 = -a
            float b = pre2 + cs2[k];   // cumsum s2 -> log w2 = -b
            float e = expf(a - b);
            float inv = 1.0f / (1.0f + e);
            w1bo[r] = inv;       // w1_bar
            w2bo[r] = e * inv;   // w2_bar
        }
    }
}

// ---------------------------------------------------------------------------
// Kernel 2: out[i][j] = f1[i]*w1b[j] + f2[i]*w2b[j]  (256 MB streaming write)
// Block owns 256 float4 columns (u,v in registers), loops over 50 rows.
// f12[i] is wave-uniform per iteration -> scalar load. One nt dwordx4
// store per row per thread; 1280 blocks total.
// ---------------------------------------------------------------------------
__global__ __launch_bounds__(256)
void anfis_out(const float2* __restrict__ f12,
               const float* __restrict__ w1b, const float* __restrict__ w2b,
               float* __restrict__ out) {
    const int j4 = blockIdx.x * 256 + threadIdx.x;  // float4 column index
    if (j4 >= NCOL4) return;                         // no barriers below
    const int i0 = blockIdx.y * ROWS_PER_BLK;

    const f32x4 u = ((const f32x4*)w1b)[j4];
    const f32x4 v = ((const f32x4*)w2b)[j4];
    f32x4* orow = (f32x4*)out + (size_t)i0 * NCOL4 + j4;

#pragma unroll 2
    for (int k = 0; k < ROWS_PER_BLK; ++k) {
        const float2 ab = f12[i0 + k];   // uniform -> s_load
        f32x4 o = ab.x * u + ab.y * v;
        __builtin_nontemporal_store(o, orow);
        orow += NCOL4;
    }
}

// ---------------------------------------------------------------------------
extern "C" void kernel_launch(void* const* d_in, const int* in_sizes, int n_in,
                              void* d_out, int out_size, void* d_ws, size_t ws_size,
                              hipStream_t stream) {
    const float* x     = (const float*)d_in[0];
    const float* a1    = (const float*)d_in[1];
    const float* c1    = (const float*)d_in[2];
    const float* a2    = (const float*)d_in[3];
    const float* c2    = (const float*)d_in[4];
    const float* w_fc1 = (const float*)d_in[5];
    const float* b_fc1 = (const float*)d_in[6];
    const float* w_fc2 = (const float*)d_in[7];
    const float* b_fc2 = (const float*)d_in[8];
    float* out = (float*)d_out;

    float* ws   = (float*)d_ws;          // 32000 floats = 128 KB used
    float* w1b  = ws;                    // [8000]
    float* w2b  = ws + 8000;             // [8000]
    float2* f12 = (float2*)(ws + 16000); // [8000] float2

    anfis_prep<<<1, SCAN_T, 0, stream>>>(x, a1, c1, a2, c2,
                                         w_fc1, b_fc1, w_fc2, b_fc2,
                                         w1b, w2b, f12);
    anfis_out<<<dim3((NCOL4 + 255) / 256, NROWS / ROWS_PER_BLK), 256, 0, stream>>>(
        f12, w1b, w2b, out);
}

// Round 4
// 274.946 us; speedup vs baseline: 1.1145x; 1.1145x over previous
//
#include <hip/hip_runtime.h>

#define NROWS 8000
#define DDIM 9
#define NCOL4 (NROWS / 4)      // 2000 float4 per output row
#define ROWS_PER_BLK 50        // 160 row-chunks in grid.y
#define NCHUNK 125             // 8000 rows / 64 rows-per-wave

typedef float f32x4 __attribute__((ext_vector_type(4)));

// ---------------------------------------------------------------------------
// K1: one wave per 64-row chunk. Per row: s = sum_j ((x-c)/a)^2, f = x.w+b.
// Wave-level inclusive scan (shuffles, no barriers) -> local cumsums cs1,cs2;
// lane 63 writes chunk totals.
// ---------------------------------------------------------------------------
__global__ __launch_bounds__(256)
void anfis_rows(const float* __restrict__ x,
                const float* __restrict__ a1p, const float* __restrict__ c1p,
                const float* __restrict__ a2p, const float* __restrict__ c2p,
                const float* __restrict__ w_fc1, const float* __restrict__ b_fc1,
                const float* __restrict__ w_fc2, const float* __restrict__ b_fc2,
                float* __restrict__ cs1o, float* __restrict__ cs2o,
                float2* __restrict__ f12o,
                float* __restrict__ t1o, float* __restrict__ t2o) {
    const int wid  = (blockIdx.x * 256 + threadIdx.x) >> 6;   // chunk id
    const int lane = threadIdx.x & 63;
    if (wid >= NCHUNK) return;
    const int r = wid * 64 + lane;

    const float inv_a1 = 1.0f / a1p[0];
    const float c1 = c1p[0];
    const float inv_a2 = 1.0f / a2p[0];
    const float c2 = c2p[0];

    float s1 = 0.f, s2 = 0.f, d1 = 0.f, d2 = 0.f;
#pragma unroll
    for (int j = 0; j < DDIM; ++j) {
        float xv = x[r * DDIM + j];
        float u1 = (xv - c1) * inv_a1;
        float u2 = (xv - c2) * inv_a2;
        s1 += u1 * u1;
        s2 += u2 * u2;
        d1 += xv * w_fc1[j];
        d2 += xv * w_fc2[j];
    }
    f12o[r] = make_float2(d1 + b_fc1[0], d2 + b_fc2[0]);

    // inclusive wave scan over 64 lanes
#pragma unroll
    for (int d = 1; d < 64; d <<= 1) {
        float n1 = __shfl_up(s1, d, 64);
        float n2 = __shfl_up(s2, d, 64);
        if (lane >= d) { s1 += n1; s2 += n2; }
    }
    cs1o[r] = s1;
    cs2o[r] = s2;
    if (lane == 63) { t1o[wid] = s1; t2o[wid] = s2; }
}

// ---------------------------------------------------------------------------
// K2: exclusive scan of the 125 chunk totals. One small block, trivial cost.
// ---------------------------------------------------------------------------
__global__ __launch_bounds__(128)
void anfis_chunkscan(const float* __restrict__ t1, const float* __restrict__ t2,
                     float* __restrict__ p1, float* __restrict__ p2) {
    __shared__ float sh1[128];
    __shared__ float sh2[128];
    const int t = threadIdx.x;
    sh1[t] = (t < NCHUNK) ? t1[t] : 0.f;
    sh2[t] = (t < NCHUNK) ? t2[t] : 0.f;
    __syncthreads();
    for (int off = 1; off < 128; off <<= 1) {
        float v1 = 0.f, v2 = 0.f;
        if (t >= off) { v1 = sh1[t - off]; v2 = sh2[t - off]; }
        __syncthreads();
        sh1[t] += v1;
        sh2[t] += v2;
        __syncthreads();
    }
    if (t < NCHUNK) {
        p1[t] = (t > 0) ? sh1[t - 1] : 0.f;   // exclusive prefix
        p2[t] = (t > 0) ? sh2[t - 1] : 0.f;
    }
}

// ---------------------------------------------------------------------------
// K3: out[i][j] = f1[i]*w1b[j] + f2[i]*w2b[j]. w1b/w2b computed in registers:
//   a = cs1[j]+P1[chunk], b = cs2[j]+P2[chunk]
//   w1b = 1/(1+exp(a-b)), w2b = 1-w1b   (log-space cumprod normalization)
// Block owns 256 float4 columns; loops ROWS_PER_BLK rows, one nt dwordx4
// store per row per thread. 4 consecutive cols never cross a 64-col chunk.
// ---------------------------------------------------------------------------
__global__ __launch_bounds__(256)
void anfis_out(const float2* __restrict__ f12,
               const float* __restrict__ cs1, const float* __restrict__ cs2,
               const float* __restrict__ p1, const float* __restrict__ p2,
               float* __restrict__ out) {
    const int j4 = blockIdx.x * 256 + threadIdx.x;  // float4 column index
    if (j4 >= NCOL4) return;
    const int c = j4 >> 4;                          // (j4*4)/64: chunk of 4 cols

    f32x4 a = ((const f32x4*)cs1)[j4] + p1[c];
    f32x4 b = ((const f32x4*)cs2)[j4] + p2[c];
    f32x4 u, v;
#pragma unroll
    for (int q = 0; q < 4; ++q) {
        float e = expf(a[q] - b[q]);
        float inv = 1.0f / (1.0f + e);
        u[q] = inv;        // w1_bar
        v[q] = e * inv;    // w2_bar
    }

    const int i0 = blockIdx.y * ROWS_PER_BLK;
    f32x4* orow = (f32x4*)out + (size_t)i0 * NCOL4 + j4;
#pragma unroll 2
    for (int k = 0; k < ROWS_PER_BLK; ++k) {
        const float2 ab = f12[i0 + k];   // block-uniform -> scalar load
        f32x4 o = ab.x * u + ab.y * v;
        __builtin_nontemporal_store(o, orow);
        orow += NCOL4;
    }
}

// ---------------------------------------------------------------------------
extern "C" void kernel_launch(void* const* d_in, const int* in_sizes, int n_in,
                              void* d_out, int out_size, void* d_ws, size_t ws_size,
                              hipStream_t stream) {
    const float* x     = (const float*)d_in[0];
    const float* a1    = (const float*)d_in[1];
    const float* c1    = (const float*)d_in[2];
    const float* a2    = (const float*)d_in[3];
    const float* c2    = (const float*)d_in[4];
    const float* w_fc1 = (const float*)d_in[5];
    const float* b_fc1 = (const float*)d_in[6];
    const float* w_fc2 = (const float*)d_in[7];
    const float* b_fc2 = (const float*)d_in[8];
    float* out = (float*)d_out;

    float* ws   = (float*)d_ws;          // 32500 floats = 130 KB used
    float* cs1  = ws;                    // [8000] local inclusive cumsums
    float* cs2  = ws + 8000;
    float2* f12 = (float2*)(ws + 16000); // [8000] float2
    float* t1   = ws + 32000;            // [125] chunk totals
    float* t2   = ws + 32125;
    float* p1   = ws + 32250;            // [125] exclusive prefixes
    float* p2   = ws + 32375;

    anfis_rows<<<(NCHUNK * 64 + 255) / 256, 256, 0, stream>>>(
        x, a1, c1, a2, c2, w_fc1, b_fc1, w_fc2, b_fc2, cs1, cs2, f12, t1, t2);
    anfis_chunkscan<<<1, 128, 0, stream>>>(t1, t2, p1, p2);
    anfis_out<<<dim3((NCOL4 + 255) / 256, NROWS / ROWS_PER_BLK), 256, 0, stream>>>(
        f12, cs1, cs2, p1, p2, out);
}

// Round 5
// 262.880 us; speedup vs baseline: 1.1657x; 1.0459x over previous
//
#include <hip/hip_runtime.h>

#define NROWS 8000
#define DDIM 9
#define NCOL4 (NROWS / 4)      // 2000 float4 per output row
#define ROWS_PER_BLK 50        // 160 row-chunks in grid.y
#define NCHUNK 125             // 8000 rows / 64 rows-per-wave

typedef float f32x4 __attribute__((ext_vector_type(4)));

// ---------------------------------------------------------------------------
// K1: one wave per 64-row chunk. Per row: s = sum_j ((x-c)/a)^2, f = x.w+b.
// Wave-level inclusive scan (shuffles, no barriers) -> local cumsums cs1,cs2;
// lane 63 writes chunk totals.
// ---------------------------------------------------------------------------
__global__ __launch_bounds__(256)
void anfis_rows(const float* __restrict__ x,
                const float* __restrict__ a1p, const float* __restrict__ c1p,
                const float* __restrict__ a2p, const float* __restrict__ c2p,
                const float* __restrict__ w_fc1, const float* __restrict__ b_fc1,
                const float* __restrict__ w_fc2, const float* __restrict__ b_fc2,
                float* __restrict__ cs1o, float* __restrict__ cs2o,
                float2* __restrict__ f12o,
                float* __restrict__ t1o, float* __restrict__ t2o) {
    const int wid  = (blockIdx.x * 256 + threadIdx.x) >> 6;   // chunk id
    const int lane = threadIdx.x & 63;
    if (wid >= NCHUNK) return;
    const int r = wid * 64 + lane;

    const float inv_a1 = 1.0f / a1p[0];
    const float c1 = c1p[0];
    const float inv_a2 = 1.0f / a2p[0];
    const float c2 = c2p[0];

    float s1 = 0.f, s2 = 0.f, d1 = 0.f, d2 = 0.f;
#pragma unroll
    for (int j = 0; j < DDIM; ++j) {
        float xv = x[r * DDIM + j];
        float u1 = (xv - c1) * inv_a1;
        float u2 = (xv - c2) * inv_a2;
        s1 += u1 * u1;
        s2 += u2 * u2;
        d1 += xv * w_fc1[j];
        d2 += xv * w_fc2[j];
    }
    f12o[r] = make_float2(d1 + b_fc1[0], d2 + b_fc2[0]);

    // inclusive wave scan over 64 lanes
#pragma unroll
    for (int d = 1; d < 64; d <<= 1) {
        float n1 = __shfl_up(s1, d, 64);
        float n2 = __shfl_up(s2, d, 64);
        if (lane >= d) { s1 += n1; s2 += n2; }
    }
    cs1o[r] = s1;
    cs2o[r] = s2;
    if (lane == 63) { t1o[wid] = s1; t2o[wid] = s2; }
}

// ---------------------------------------------------------------------------
// K2: out[i][j] = f1[i]*w1b[j] + f2[i]*w2b[j].
// Each block first redundantly scans the 125 chunk totals in LDS (cheap:
// 1 KB from L2 + 7 Hillis steps), so no separate chunk-scan dispatch.
// Then w1b/w2b in registers:
//   a = cs1[j]+P1[chunk], b = cs2[j]+P2[chunk]
//   w1b = 1/(1+exp(a-b)), w2b = 1-w1b   (log-space cumprod normalization)
// Block owns 256 float4 columns; loops ROWS_PER_BLK rows, plain dwordx4
// stores (fill kernel sustains 6.4 TB/s with plain stores). No early return
// (barriers below) — guard with `valid` instead.
// ---------------------------------------------------------------------------
__global__ __launch_bounds__(256)
void anfis_out(const float2* __restrict__ f12,
               const float* __restrict__ cs1, const float* __restrict__ cs2,
               const float* __restrict__ t1, const float* __restrict__ t2,
               float* __restrict__ out) {
    __shared__ float sh1[128];
    __shared__ float sh2[128];
    const int tid = threadIdx.x;

    if (tid < 128) {
        sh1[tid] = (tid < NCHUNK) ? t1[tid] : 0.f;
        sh2[tid] = (tid < NCHUNK) ? t2[tid] : 0.f;
    }
    __syncthreads();
    for (int off = 1; off < 128; off <<= 1) {
        float v1 = 0.f, v2 = 0.f;
        if (tid < 128 && tid >= off) { v1 = sh1[tid - off]; v2 = sh2[tid - off]; }
        __syncthreads();
        if (tid < 128) { sh1[tid] += v1; sh2[tid] += v2; }
        __syncthreads();
    }

    const int j4 = blockIdx.x * 256 + tid;   // float4 column index
    const bool valid = (j4 < NCOL4);
    const int c = j4 >> 4;                   // (j4*4)/64: chunk of these 4 cols

    f32x4 u, v;
    if (valid) {
        const float pre1 = (c > 0) ? sh1[c - 1] : 0.f;   // exclusive prefix
        const float pre2 = (c > 0) ? sh2[c - 1] : 0.f;
        f32x4 a = ((const f32x4*)cs1)[j4] + pre1;
        f32x4 b = ((const f32x4*)cs2)[j4] + pre2;
#pragma unroll
        for (int q = 0; q < 4; ++q) {
            float e = expf(a[q] - b[q]);
            float inv = 1.0f / (1.0f + e);
            u[q] = inv;        // w1_bar
            v[q] = e * inv;    // w2_bar
        }
    }

    const int i0 = blockIdx.y * ROWS_PER_BLK;
    f32x4* orow = (f32x4*)out + (size_t)i0 * NCOL4 + j4;
#pragma unroll 4
    for (int k = 0; k < ROWS_PER_BLK; ++k) {
        const float2 ab = f12[i0 + k];   // block-uniform -> scalar load
        if (valid) {
            f32x4 o = ab.x * u + ab.y * v;
            *orow = o;
        }
        orow += NCOL4;
    }
}

// ---------------------------------------------------------------------------
extern "C" void kernel_launch(void* const* d_in, const int* in_sizes, int n_in,
                              void* d_out, int out_size, void* d_ws, size_t ws_size,
                              hipStream_t stream) {
    const float* x     = (const float*)d_in[0];
    const float* a1    = (const float*)d_in[1];
    const float* c1    = (const float*)d_in[2];
    const float* a2    = (const float*)d_in[3];
    const float* c2    = (const float*)d_in[4];
    const float* w_fc1 = (const float*)d_in[5];
    const float* b_fc1 = (const float*)d_in[6];
    const float* w_fc2 = (const float*)d_in[7];
    const float* b_fc2 = (const float*)d_in[8];
    float* out = (float*)d_out;

    float* ws   = (float*)d_ws;          // ~130 KB used
    float* cs1  = ws;                    // [8000] local inclusive cumsums
    float* cs2  = ws + 8000;
    float2* f12 = (float2*)(ws + 16000); // [8000] float2
    float* t1   = ws + 32000;            // [125] chunk totals
    float* t2   = ws + 32125;

    anfis_rows<<<(NCHUNK * 64 + 255) / 256, 256, 0, stream>>>(
        x, a1, c1, a2, c2, w_fc1, b_fc1, w_fc2, b_fc2, cs1, cs2, f12, t1, t2);
    anfis_out<<<dim3((NCOL4 + 255) / 256, NROWS / ROWS_PER_BLK), 256, 0, stream>>>(
        f12, cs1, cs2, t1, t2, out);
}